// Round 9
// baseline (217.576 us; speedup 1.0000x reference)
//
#include <hip/hip_runtime.h>
#include <cstdint>

#define DEV __device__ __forceinline__

typedef __attribute__((ext_vector_type(4))) float f32x4;
typedef __attribute__((ext_vector_type(8))) short short8;
typedef __attribute__((ext_vector_type(4))) unsigned short u16x4;

constexpr int BS  = 4;
constexpr int SEQ = 2048;

DEV ushort f2b(float f){
  uint32_t u = __builtin_bit_cast(uint32_t, f);
  u += 0x7fffu + ((u >> 16) & 1u);
  return (ushort)(u >> 16);
}
DEV float b2f(ushort h){
  uint32_t u = (uint32_t)h << 16;
  return __builtin_bit_cast(float, u);
}

DEV void gload_lds16(const void* g, void* l){
  __builtin_amdgcn_global_load_lds(
      (const __attribute__((address_space(1))) unsigned int*)g,
      (__attribute__((address_space(3))) unsigned int*)l, 16, 0, 0);
}

#define BAR()    __builtin_amdgcn_s_barrier()
#define PRIO(x)  __builtin_amdgcn_s_setprio(x)
#define SCHEDB() __builtin_amdgcn_sched_barrier(0)
#define LGKM0()  asm volatile("s_waitcnt lgkmcnt(0)" ::: "memory")
#define WAITV(n) asm volatile("s_waitcnt vmcnt(" #n ")" ::: "memory")

// ---------- fp32 -> bf16 convert ----------
__global__ __launch_bounds__(256) void convert_f2b8(const float* __restrict__ src,
                                                    ushort* __restrict__ dst){
  long i = (long)blockIdx.x * 256 + threadIdx.x;
  const f32x4* s4 = (const f32x4*)src;
  f32x4 a = s4[i*2], b = s4[i*2+1];
  short8 o;
  o[0]=(short)f2b(a[0]); o[1]=(short)f2b(a[1]); o[2]=(short)f2b(a[2]); o[3]=(short)f2b(a[3]);
  o[4]=(short)f2b(b[0]); o[5]=(short)f2b(b[1]); o[6]=(short)f2b(b[2]); o[7]=(short)f2b(b[3]);
  ((short8*)dst)[i] = o;
}

// ---------- fused transpose fp32 [1024][1024] -> bf16 ^T, 3 weights ----------
__global__ __launch_bounds__(256) void transpose_f2b3(const float* __restrict__ w0,
                                                      const float* __restrict__ w1,
                                                      const float* __restrict__ w2,
                                                      ushort* __restrict__ dst){
  __shared__ float t[32][33];
  const int zz = blockIdx.z;
  const float* src = (zz == 0) ? w0 : (zz == 1) ? w1 : w2;
  ushort* d = dst + (long)zz * 1048576;
  int c0 = blockIdx.x * 32, r0 = blockIdx.y * 32;
  int tx = threadIdx.x, ty = threadIdx.y;
  #pragma unroll
  for (int k=0;k<4;k++) t[ty+k*8][tx] = src[(long)(r0+ty+k*8)*1024 + c0+tx];
  __syncthreads();
  #pragma unroll
  for (int k=0;k<4;k++) d[(long)(c0+ty+k*8)*1024 + r0+tx] = f2b(t[tx][ty+k*8]);
}

// ---------- transpose bf16 [R][C] -> bf16 [C][R] ----------
__global__ __launch_bounds__(256) void transpose_b2b(const ushort* __restrict__ src,
                                                     ushort* __restrict__ dst,
                                                     int R, int C){
  __shared__ ushort t[32][33];
  int c0 = blockIdx.x * 32, r0 = blockIdx.y * 32;
  int tx = threadIdx.x, ty = threadIdx.y;
  #pragma unroll
  for (int k=0;k<4;k++) t[ty+k*8][tx] = src[(long)(r0+ty+k*8)*C + c0+tx];
  __syncthreads();
  #pragma unroll
  for (int k=0;k<4;k++) dst[(long)(c0+ty+k*8)*R + r0+tx] = t[tx][ty+k*8];
}

struct GArgs {
  const ushort* A;  long lda; long aBS;
  const ushort* Bm; long ldb; long bBS;
  void* C;          long ldc; long cBS;
  const float* b0; const float* b1; const float* b2;
  int K;
};

// =====================================================================
// gemmA_qkv: 256x192 tile, BK=64, 8 waves, 4-phase/K-tile (r4, measured 67us)
// =====================================================================
__global__ __launch_bounds__(512, 2) void gemmA_qkv(GArgs g){
  extern __shared__ char sm[];
  const int tid = threadIdx.x;
  const int wid = tid >> 6, lane = tid & 63;
  const int wr = wid >> 2, wc = wid & 3;
  const int lr = lane & 15, lk = lane >> 4;
  const int f5 = ((lr >> 3) & 1) << 5;

  const int fid = blockIdx.x;                 // 512 blocks
  const int xcd = fid & 7, j = fid >> 3;
  const int m0 = (xcd * 4 + (j & 3)) * 256;
  const int n0 = (j >> 2) * 192;

  const long lda2 = g.lda * 2, ldb2 = g.ldb * 2;
  const int skk = tid >> 8;
  const int srr = (tid >> 2) & 63;
  const int scc = tid & 3;
  const int scb = (scc * 16) ^ (((srr >> 3) & 1) << 5);
  const char* aU0 = (const char*)g.A  + (long)(m0       + srr)*lda2 + skk*64 + scb;
  const char* aU1 = (const char*)g.A  + (long)(m0 +  64 + srr)*lda2 + skk*64 + scb;
  const char* aU2 = (const char*)g.A  + (long)(m0 + 128 + srr)*lda2 + skk*64 + scb;
  const char* aU3 = (const char*)g.A  + (long)(m0 + 192 + srr)*lda2 + skk*64 + scb;
  const char* bU0 = (const char*)g.Bm + (long)(n0       + srr)*ldb2 + skk*64 + scb;
  const char* bU1 = (const char*)g.Bm + (long)(n0 +  64 + srr)*ldb2 + skk*64 + scb;
  const char* bU2 = (const char*)g.Bm + (long)(n0 + 128 + srr)*ldb2 + skk*64 + scb;
  const int dst = tid * 16;

#define STA(u, cb, k0) gload_lds16(aU##u + (k0)*2, sm + (cb)*57344 + u*8192 + dst)
#define STB(u, cb, k0) gload_lds16(bU##u + (k0)*2, sm + (cb)*57344 + 32768 + u*8192 + dst)

  int aoff[8], boff[3];
  #pragma unroll
  for (int mm=0;mm<8;mm++)
    aoff[mm] = wr*16384 + (mm>>2)*8192 + (mm&3)*1024 + lr*64 + ((lk*16) ^ f5);
  #pragma unroll
  for (int nn=0;nn<3;nn++){
    int br = wc*48 + nn*16 + lr;
    boff[nn] = 32768 + (br>>6)*8192 + (br&63)*64 + ((lk*16) ^ f5);
  }

  f32x4 acc[8][3];
  #pragma unroll
  for (int m=0;m<8;m++)
    #pragma unroll
    for (int n=0;n<3;n++) acc[m][n] = f32x4{0.f,0.f,0.f,0.f};

  const int NT = g.K >> 6;
  STA(0,0,0); STA(1,0,0); STA(2,0,0); STA(3,0,0);
  STB(0,0,0); STB(1,0,0); STB(2,0,0);
  STB(0,1,64); STB(1,1,64); STB(2,1,64);
  WAITV(3); BAR();

  short8 bf[3][2], af[2][2];
#define READ_AF(MB) \
    af[0][0] = *(const short8*)(base + aoff[MB  ]);        \
    af[0][1] = *(const short8*)(base + aoff[MB  ] + 4096); \
    af[1][0] = *(const short8*)(base + aoff[MB+1]);        \
    af[1][1] = *(const short8*)(base + aoff[MB+1] + 4096);
#define MFMA6(MB) \
    PRIO(1); \
    _Pragma("unroll") \
    for (int kk=0;kk<2;kk++) \
      _Pragma("unroll") \
      for (int mm=0;mm<2;mm++) \
        _Pragma("unroll") \
        for (int nn=0;nn<3;nn++) \
          acc[MB+mm][nn] = __builtin_amdgcn_mfma_f32_16x16x32_bf16(af[mm][kk], bf[nn][kk], acc[MB+mm][nn], 0,0,0); \
    PRIO(0);

  for (int t = 0; t < NT; ++t){
    const int c = t & 1;
    const char* base = sm + c*57344;
    const int kA = ((t+1) < NT ? (t+1) : NT-1) << 6;
    const int kB = ((t+2) < NT ? (t+2) : NT-1) << 6;
    STA(0, c^1, kA); STA(1, c^1, kA);
    #pragma unroll
    for (int nn=0;nn<3;nn++){
      bf[nn][0] = *(const short8*)(base + boff[nn]);
      bf[nn][1] = *(const short8*)(base + boff[nn] + 4096);
    }
    READ_AF(0);
    LGKM0(); SCHEDB();
    MFMA6(0);
    BAR();
    STA(2, c^1, kA); STA(3, c^1, kA);
    READ_AF(2);
    LGKM0(); SCHEDB();
    MFMA6(2);
    BAR();
    STB(0, c, kB); STB(1, c, kB);
    READ_AF(4);
    LGKM0(); SCHEDB();
    MFMA6(4);
    BAR();
    STB(2, c, kB);
    READ_AF(6);
    LGKM0(); SCHEDB();
    MFMA6(6);
    WAITV(3);
    BAR();
  }
  WAITV(0);
#undef STA
#undef STB
#undef READ_AF
#undef MFMA6

  #pragma unroll
  for (int nn=0;nn<3;nn++){
    int col  = n0 + wc*48 + nn*16 + lr;
    int sel  = col >> 10;
    int colq = col & 1023;
    const float* bp = (sel == 0) ? g.b0 : (sel == 1) ? g.b1 : g.b2;
    float bv = bp[colq];
    ushort* Cq = (ushort*)g.C + (long)sel * 8388608;
    #pragma unroll
    for (int mm=0;mm<8;mm++){
      int row0 = m0 + wr*128 + mm*16 + lk*4;
      #pragma unroll
      for (int i=0;i<4;i++)
        Cq[(long)(row0+i)*1024 + colq] = f2b(acc[mm][nn][i] + bv);
    }
  }
}

// =====================================================================
// scoresE: r1-proven 128x128 2-phase dbuf GEMM (BK=32, 256 thr, 32KB LDS)
// C = exp(q@k^T / 32), causal-masked bf16. Grid (16,16,BS); 544 live
// blocks, multi-block/CU -> all CUs busy (fixes 56%-idle 256^2 version).
// =====================================================================
__global__ __launch_bounds__(256) void scoresE(GArgs g){
  __shared__ ushort aL[2][128*32];
  __shared__ ushort bL[2][128*32];
  int m0 = blockIdx.x * 128, n0 = blockIdx.y * 128;
  int z  = blockIdx.z;
  if (n0 > m0) return;                            // fully masked tile
  const char* Ab = (const char*)(g.A  + (long)z * g.aBS);
  const char* Bb = (const char*)(g.Bm + (long)z * g.bBS);
  int tid = threadIdx.x;
  int wid = tid >> 6, lane = tid & 63;
  int wr = wid >> 1, wc = wid & 1;
  int lr = lane & 15, lk = lane >> 4;

  int ob0 = (0*4 + wid) * 1024;
  int ob1 = (1*4 + wid) * 1024;
  int o0  = ob0 + (lane << 4);
  int o1  = ob1 + (lane << 4);
  int r0_ = o0 >> 6, cb0 = o0 & 63;
  int r1_ = o1 >> 6, cb1 = o1 & 63;

  auto stage = [&](int buf, int k0){
    gload_lds16(Ab + ((long)(m0+r0_)*g.lda + k0)*2 + cb0, (char*)aL[buf] + ob0);
    gload_lds16(Bb + ((long)(n0+r0_)*g.ldb + k0)*2 + cb0, (char*)bL[buf] + ob0);
    gload_lds16(Ab + ((long)(m0+r1_)*g.lda + k0)*2 + cb1, (char*)aL[buf] + ob1);
    gload_lds16(Bb + ((long)(n0+r1_)*g.ldb + k0)*2 + cb1, (char*)bL[buf] + ob1);
  };

  f32x4 acc[4][4];
  #pragma unroll
  for (int m=0;m<4;m++)
    #pragma unroll
    for (int n=0;n<4;n++) acc[m][n] = f32x4{0.f,0.f,0.f,0.f};

  int nt = g.K >> 5;
  stage(0, 0);
  __syncthreads();
  int cur = 0;
  for (int t = 0; t < nt-1; ++t){
    stage(cur ^ 1, (t+1) << 5);
    short8 af[4], bf4[4];
    #pragma unroll
    for (int m=0;m<4;m++) af[m]  = *(const short8*)&aL[cur][(wr*64 + m*16 + lr)*32 + lk*8];
    #pragma unroll
    for (int n=0;n<4;n++) bf4[n] = *(const short8*)&bL[cur][(wc*64 + n*16 + lr)*32 + lk*8];
    #pragma unroll
    for (int m=0;m<4;m++)
      #pragma unroll
      for (int n=0;n<4;n++)
        acc[m][n] = __builtin_amdgcn_mfma_f32_16x16x32_bf16(af[m], bf4[n], acc[m][n], 0, 0, 0);
    __syncthreads();
    cur ^= 1;
  }
  {
    short8 af[4], bf4[4];
    #pragma unroll
    for (int m=0;m<4;m++) af[m]  = *(const short8*)&aL[cur][(wr*64 + m*16 + lr)*32 + lk*8];
    #pragma unroll
    for (int n=0;n<4;n++) bf4[n] = *(const short8*)&bL[cur][(wc*64 + n*16 + lr)*32 + lk*8];
    #pragma unroll
    for (int m=0;m<4;m++)
      #pragma unroll
      for (int n=0;n<4;n++)
        acc[m][n] = __builtin_amdgcn_mfma_f32_16x16x32_bf16(af[m], bf4[n], acc[m][n], 0, 0, 0);
  }

  const float scale = 0.03125f;
  ushort* Cs = (ushort*)g.C + (long)z * g.cBS;
  #pragma unroll
  for (int m=0;m<4;m++){
    int row0 = m0 + wr*64 + m*16 + lk*4;
    #pragma unroll
    for (int n=0;n<4;n++){
      int col = n0 + wc*64 + n*16 + lr;
      #pragma unroll
      for (int i=0;i<4;i++){
        int row = row0 + i;
        float e = (col <= row) ? __expf(acc[m][n][i] * scale) : 0.0f;
        Cs[(long)row*g.ldc + col] = f2b(e);
      }
    }
  }
}

// ---------- rowsum: inv[b][row] = 1 / sum_k P_un[b][row][k] ----------
__global__ __launch_bounds__(256) void rowsum_inv(const ushort* __restrict__ P,
                                                  float* __restrict__ inv){
  int row = blockIdx.x & (SEQ-1);
  int b   = blockIdx.x >> 11;
  const short8* pr = (const short8*)(P + ((long)b*SEQ + row)*(long)SEQ);
  int tid = threadIdx.x;
  int lane = tid & 63, wid = tid >> 6;
  float s = 0.f;
  if (tid*8 <= row){
    short8 v = pr[tid];
    #pragma unroll
    for (int j=0;j<8;j++) s += b2f((ushort)v[j]);
  }
  #pragma unroll
  for (int off=1; off<64; off<<=1) s += __shfl_xor(s, off);
  __shared__ float rb[4];
  if (lane == 0) rb[wid] = s;
  __syncthreads();
  if (tid == 0){
    float tot = (rb[0]+rb[1]) + (rb[2]+rb[3]);
    inv[(long)b*SEQ + row] = 1.0f / tot;
  }
}

// =====================================================================
// pvPair: balanced PV. Block handles m-tiles {x, 15-x} sequentially at
// BN=128 -> every block does exactly 2176 K-steps (uniform; kills the
// 16x Keff imbalance). r1-proven 2-phase structure. out *= inv[row].
// Grid (8, 8, BS).
// =====================================================================
__global__ __launch_bounds__(256) void pvPair(GArgs g){
  __shared__ ushort aL[2][128*32];
  __shared__ ushort bL[2][128*32];
  const int px = blockIdx.x;
  const int n0 = blockIdx.y * 128;
  const int z  = blockIdx.z;
  const char* Ab = (const char*)(g.A  + (long)z * g.aBS);
  const char* Bb = (const char*)(g.Bm + (long)z * g.bBS);
  const float* invp = g.b0 + (long)z * SEQ;
  float* Co = (float*)g.C + (long)z * g.cBS;
  int tid = threadIdx.x;
  int wid = tid >> 6, lane = tid & 63;
  int wr = wid >> 1, wc = wid & 1;
  int lr = lane & 15, lk = lane >> 4;

  int ob0 = (0*4 + wid) * 1024;
  int ob1 = (1*4 + wid) * 1024;
  int o0  = ob0 + (lane << 4);
  int o1  = ob1 + (lane << 4);
  int r0_ = o0 >> 6, cb0 = o0 & 63;
  int r1_ = o1 >> 6, cb1 = o1 & 63;

  #pragma unroll
  for (int half = 0; half < 2; ++half){
    const int mt = half ? (15 - px) : px;
    const int m0 = mt * 128;
    const int Keff = m0 + 128;

    auto stage = [&](int buf, int k0){
      gload_lds16(Ab + ((long)(m0+r0_)*g.lda + k0)*2 + cb0, (char*)aL[buf] + ob0);
      gload_lds16(Bb + ((long)(n0+r0_)*g.ldb + k0)*2 + cb0, (char*)bL[buf] + ob0);
      gload_lds16(Ab + ((long)(m0+r1_)*g.lda + k0)*2 + cb1, (char*)aL[buf] + ob1);
      gload_lds16(Bb + ((long)(n0+r1_)*g.ldb + k0)*2 + cb1, (char*)bL[buf] + ob1);
    };

    f32x4 acc[4][4];
    #pragma unroll
    for (int m=0;m<4;m++)
      #pragma unroll
      for (int n=0;n<4;n++) acc[m][n] = f32x4{0.f,0.f,0.f,0.f};

    int nt = Keff >> 5;
    stage(0, 0);
    __syncthreads();
    int cur = 0;
    for (int t = 0; t < nt-1; ++t){
      stage(cur ^ 1, (t+1) << 5);
      short8 af[4], bf4[4];
      #pragma unroll
      for (int m=0;m<4;m++) af[m]  = *(const short8*)&aL[cur][(wr*64 + m*16 + lr)*32 + lk*8];
      #pragma unroll
      for (int n=0;n<4;n++) bf4[n] = *(const short8*)&bL[cur][(wc*64 + n*16 + lr)*32 + lk*8];
      #pragma unroll
      for (int m=0;m<4;m++)
        #pragma unroll
        for (int n=0;n<4;n++)
          acc[m][n] = __builtin_amdgcn_mfma_f32_16x16x32_bf16(af[m], bf4[n], acc[m][n], 0, 0, 0);
      __syncthreads();
      cur ^= 1;
    }
    {
      short8 af[4], bf4[4];
      #pragma unroll
      for (int m=0;m<4;m++) af[m]  = *(const short8*)&aL[cur][(wr*64 + m*16 + lr)*32 + lk*8];
      #pragma unroll
      for (int n=0;n<4;n++) bf4[n] = *(const short8*)&bL[cur][(wc*64 + n*16 + lr)*32 + lk*8];
      #pragma unroll
      for (int m=0;m<4;m++)
        #pragma unroll
        for (int n=0;n<4;n++)
          acc[m][n] = __builtin_amdgcn_mfma_f32_16x16x32_bf16(af[m], bf4[n], acc[m][n], 0, 0, 0);
    }

    #pragma unroll
    for (int m=0;m<4;m++){
      int row0 = m0 + wr*64 + m*16 + lk*4;
      #pragma unroll
      for (int n=0;n<4;n++){
        int col = n0 + wc*64 + n*16 + lr;
        #pragma unroll
        for (int i=0;i<4;i++)
          Co[(long)(row0+i)*g.ldc + col] = acc[m][n][i] * invp[row0+i];
      }
    }
    __syncthreads();   // all waves done reading LDS before half-2 restages
  }
}

extern "C" void kernel_launch(void* const* d_in, const int* in_sizes, int n_in,
                              void* d_out, int out_size, void* d_ws, size_t ws_size,
                              hipStream_t stream){
  const float* x  = (const float*)d_in[0];
  const float* Wq = (const float*)d_in[1];
  const float* Wk = (const float*)d_in[2];
  const float* Wv = (const float*)d_in[3];
  const float* bq = (const float*)d_in[4];
  const float* bk = (const float*)d_in[5];
  const float* bv = (const float*)d_in[6];
  float* out = (float*)d_out;

  const long XB = 0;            // x bf16 [8192][1024]          16 MB
  const long WT = 16777216;     // Wt bf16 x3 [1024][1024]       6 MB
  const long QB = 23068672;     // q/k/v bf16 contiguous        48 MB
  const long VT = 73400320;     // v^T bf16 [1024][8192]        16 MB
  const long PU = 90177536;     // P_un bf16 [4][2048][2048]    32 MB
  const long IV = 123731968;    // inv rowsum fp32 [4][2048]    32 KB
  const long NEED = 123764736;
  if ((long)ws_size < NEED) return;

  char* ws = (char*)d_ws;
  ushort* xb = (ushort*)(ws + XB);
  ushort* wt = (ushort*)(ws + WT);
  ushort* qb = (ushort*)(ws + QB);
  ushort* kb = qb + 8388608;
  ushort* vb = qb + 16777216;
  ushort* vt = (ushort*)(ws + VT);
  ushort* pu = (ushort*)(ws + PU);
  float*  iv = (float* )(ws + IV);

  hipFuncSetAttribute(reinterpret_cast<const void*>(&gemmA_qkv),
                      hipFuncAttributeMaxDynamicSharedMemorySize, 114688);

  dim3 tb(32, 8);

  convert_f2b8<<<4096, 256, 0, stream>>>(x, xb);
  transpose_f2b3<<<dim3(32,32,3), tb, 0, stream>>>(Wq, Wk, Wv, wt);

  // fused projections: [q|k|v] = x @ [Wq|Wk|Wv] + bias, M=8192 N=3072 K=1024
  GArgs pa{};
  pa.A = xb; pa.lda = 1024; pa.aBS = 0;
  pa.Bm = wt; pa.ldb = 1024; pa.bBS = 0;
  pa.C = (void*)qb; pa.ldc = 1024; pa.cBS = 0;
  pa.b0 = bq; pa.b1 = bk; pa.b2 = bv;
  pa.K = 1024;
  gemmA_qkv<<<512, 512, 114688, stream>>>(pa);

  transpose_b2b<<<dim3(32,256), tb, 0, stream>>>(vb, vt, 8192, 1024);

  // P_un = exp(q @ k^T / 32), causal-masked, bf16; 128^2 tiles
  GArgs sa{};
  sa.A = qb;  sa.lda = 1024; sa.aBS = (long)SEQ*1024;
  sa.Bm = kb; sa.ldb = 1024; sa.bBS = (long)SEQ*1024;
  sa.C = (void*)pu; sa.ldc = SEQ; sa.cBS = (long)SEQ*SEQ;
  sa.b0 = nullptr; sa.b1 = nullptr; sa.b2 = nullptr;
  sa.K = 1024;
  scoresE<<<dim3(16,16,BS), 256, 0, stream>>>(sa);

  rowsum_inv<<<BS*SEQ, 256, 0, stream>>>(pu, iv);

  // out = (P_un @ V) * inv, balanced pair-blocks
  GArgs va{};
  va.A = pu;  va.lda = SEQ;  va.aBS = (long)SEQ*SEQ;
  va.Bm = vt; va.ldb = 8192; va.bBS = SEQ;
  va.C = (void*)out; va.ldc = 1024; va.cBS = (long)SEQ*1024;
  va.b0 = iv; va.b1 = nullptr; va.b2 = nullptr;
  va.K = SEQ;
  pvPair<<<dim3(8,8,BS), 256, 0, stream>>>(va);
}

// Round 11
// 175.762 us; speedup vs baseline: 1.2379x; 1.2379x over previous
//
#include <hip/hip_runtime.h>
#include <cstdint>

#define DEV __device__ __forceinline__

typedef __attribute__((ext_vector_type(4))) float f32x4;
typedef __attribute__((ext_vector_type(8))) short short8;
typedef __attribute__((ext_vector_type(4))) unsigned short u16x4;

constexpr int BS  = 4;
constexpr int SEQ = 2048;

DEV ushort f2b(float f){
  uint32_t u = __builtin_bit_cast(uint32_t, f);
  u += 0x7fffu + ((u >> 16) & 1u);
  return (ushort)(u >> 16);
}
DEV float b2f(ushort h){
  uint32_t u = (uint32_t)h << 16;
  return __builtin_bit_cast(float, u);
}

DEV void gload_lds16(const void* g, void* l){
  __builtin_amdgcn_global_load_lds(
      (const __attribute__((address_space(1))) unsigned int*)g,
      (__attribute__((address_space(3))) unsigned int*)l, 16, 0, 0);
}

#define BAR()    __builtin_amdgcn_s_barrier()
#define PRIO(x)  __builtin_amdgcn_s_setprio(x)
#define SCHEDB() __builtin_amdgcn_sched_barrier(0)
#define LGKM0()  asm volatile("s_waitcnt lgkmcnt(0)" ::: "memory")
#define WAITV(n) asm volatile("s_waitcnt vmcnt(" #n ")" ::: "memory")

// ---------- fp32 -> bf16 convert ----------
__global__ __launch_bounds__(256) void convert_f2b8(const float* __restrict__ src,
                                                    ushort* __restrict__ dst){
  long i = (long)blockIdx.x * 256 + threadIdx.x;
  const f32x4* s4 = (const f32x4*)src;
  f32x4 a = s4[i*2], b = s4[i*2+1];
  short8 o;
  o[0]=(short)f2b(a[0]); o[1]=(short)f2b(a[1]); o[2]=(short)f2b(a[2]); o[3]=(short)f2b(a[3]);
  o[4]=(short)f2b(b[0]); o[5]=(short)f2b(b[1]); o[6]=(short)f2b(b[2]); o[7]=(short)f2b(b[3]);
  ((short8*)dst)[i] = o;
}

// ---------- fused transpose fp32 [1024][1024] -> bf16 ^T, 3 weights ----------
__global__ __launch_bounds__(256) void transpose_f2b3(const float* __restrict__ w0,
                                                      const float* __restrict__ w1,
                                                      const float* __restrict__ w2,
                                                      ushort* __restrict__ dst){
  __shared__ float t[32][33];
  const int zz = blockIdx.z;
  const float* src = (zz == 0) ? w0 : (zz == 1) ? w1 : w2;
  ushort* d = dst + (long)zz * 1048576;
  int c0 = blockIdx.x * 32, r0 = blockIdx.y * 32;
  int tx = threadIdx.x, ty = threadIdx.y;
  #pragma unroll
  for (int k=0;k<4;k++) t[ty+k*8][tx] = src[(long)(r0+ty+k*8)*1024 + c0+tx];
  __syncthreads();
  #pragma unroll
  for (int k=0;k<4;k++) d[(long)(c0+ty+k*8)*1024 + r0+tx] = f2b(t[tx][ty+k*8]);
}

// ---------- transpose bf16 [R][C] -> bf16 [C][R] ----------
__global__ __launch_bounds__(256) void transpose_b2b(const ushort* __restrict__ src,
                                                     ushort* __restrict__ dst,
                                                     int R, int C){
  __shared__ ushort t[32][33];
  int c0 = blockIdx.x * 32, r0 = blockIdx.y * 32;
  int tx = threadIdx.x, ty = threadIdx.y;
  #pragma unroll
  for (int k=0;k<4;k++) t[ty+k*8][tx] = src[(long)(r0+ty+k*8)*C + c0+tx];
  __syncthreads();
  #pragma unroll
  for (int k=0;k<4;k++) dst[(long)(c0+ty+k*8)*R + r0+tx] = t[tx][ty+k*8];
}

struct GArgs {
  const ushort* A;  long lda; long aBS;
  const ushort* Bm; long ldb; long bBS;
  void* C;          long ldc; long cBS;
  const float* b0; const float* b1; const float* b2;
  int K;
};

// =====================================================================
// gemmA_qkv: 256x192 tile, BK=64, 8 waves, 4-phase/K-tile (r4, measured 67us)
// =====================================================================
__global__ __launch_bounds__(512, 2) void gemmA_qkv(GArgs g){
  extern __shared__ char sm[];
  const int tid = threadIdx.x;
  const int wid = tid >> 6, lane = tid & 63;
  const int wr = wid >> 2, wc = wid & 3;
  const int lr = lane & 15, lk = lane >> 4;
  const int f5 = ((lr >> 3) & 1) << 5;

  const int fid = blockIdx.x;                 // 512 blocks
  const int xcd = fid & 7, j = fid >> 3;
  const int m0 = (xcd * 4 + (j & 3)) * 256;
  const int n0 = (j >> 2) * 192;

  const long lda2 = g.lda * 2, ldb2 = g.ldb * 2;
  const int skk = tid >> 8;
  const int srr = (tid >> 2) & 63;
  const int scc = tid & 3;
  const int scb = (scc * 16) ^ (((srr >> 3) & 1) << 5);
  const char* aU0 = (const char*)g.A  + (long)(m0       + srr)*lda2 + skk*64 + scb;
  const char* aU1 = (const char*)g.A  + (long)(m0 +  64 + srr)*lda2 + skk*64 + scb;
  const char* aU2 = (const char*)g.A  + (long)(m0 + 128 + srr)*lda2 + skk*64 + scb;
  const char* aU3 = (const char*)g.A  + (long)(m0 + 192 + srr)*lda2 + skk*64 + scb;
  const char* bU0 = (const char*)g.Bm + (long)(n0       + srr)*ldb2 + skk*64 + scb;
  const char* bU1 = (const char*)g.Bm + (long)(n0 +  64 + srr)*ldb2 + skk*64 + scb;
  const char* bU2 = (const char*)g.Bm + (long)(n0 + 128 + srr)*ldb2 + skk*64 + scb;
  const int dst = tid * 16;

#define STA(u, cb, k0) gload_lds16(aU##u + (k0)*2, sm + (cb)*57344 + u*8192 + dst)
#define STB(u, cb, k0) gload_lds16(bU##u + (k0)*2, sm + (cb)*57344 + 32768 + u*8192 + dst)

  int aoff[8], boff[3];
  #pragma unroll
  for (int mm=0;mm<8;mm++)
    aoff[mm] = wr*16384 + (mm>>2)*8192 + (mm&3)*1024 + lr*64 + ((lk*16) ^ f5);
  #pragma unroll
  for (int nn=0;nn<3;nn++){
    int br = wc*48 + nn*16 + lr;
    boff[nn] = 32768 + (br>>6)*8192 + (br&63)*64 + ((lk*16) ^ f5);
  }

  f32x4 acc[8][3];
  #pragma unroll
  for (int m=0;m<8;m++)
    #pragma unroll
    for (int n=0;n<3;n++) acc[m][n] = f32x4{0.f,0.f,0.f,0.f};

  const int NT = g.K >> 6;
  STA(0,0,0); STA(1,0,0); STA(2,0,0); STA(3,0,0);
  STB(0,0,0); STB(1,0,0); STB(2,0,0);
  STB(0,1,64); STB(1,1,64); STB(2,1,64);
  WAITV(3); BAR();

  short8 bf[3][2], af[2][2];
#define READ_AF(MB) \
    af[0][0] = *(const short8*)(base + aoff[MB  ]);        \
    af[0][1] = *(const short8*)(base + aoff[MB  ] + 4096); \
    af[1][0] = *(const short8*)(base + aoff[MB+1]);        \
    af[1][1] = *(const short8*)(base + aoff[MB+1] + 4096);
#define MFMA6(MB) \
    PRIO(1); \
    _Pragma("unroll") \
    for (int kk=0;kk<2;kk++) \
      _Pragma("unroll") \
      for (int mm=0;mm<2;mm++) \
        _Pragma("unroll") \
        for (int nn=0;nn<3;nn++) \
          acc[MB+mm][nn] = __builtin_amdgcn_mfma_f32_16x16x32_bf16(af[mm][kk], bf[nn][kk], acc[MB+mm][nn], 0,0,0); \
    PRIO(0);

  for (int t = 0; t < NT; ++t){
    const int c = t & 1;
    const char* base = sm + c*57344;
    const int kA = ((t+1) < NT ? (t+1) : NT-1) << 6;
    const int kB = ((t+2) < NT ? (t+2) : NT-1) << 6;
    STA(0, c^1, kA); STA(1, c^1, kA);
    #pragma unroll
    for (int nn=0;nn<3;nn++){
      bf[nn][0] = *(const short8*)(base + boff[nn]);
      bf[nn][1] = *(const short8*)(base + boff[nn] + 4096);
    }
    READ_AF(0);
    LGKM0(); SCHEDB();
    MFMA6(0);
    BAR();
    STA(2, c^1, kA); STA(3, c^1, kA);
    READ_AF(2);
    LGKM0(); SCHEDB();
    MFMA6(2);
    BAR();
    STB(0, c, kB); STB(1, c, kB);
    READ_AF(4);
    LGKM0(); SCHEDB();
    MFMA6(4);
    BAR();
    STB(2, c, kB);
    READ_AF(6);
    LGKM0(); SCHEDB();
    MFMA6(6);
    WAITV(3);
    BAR();
  }
  WAITV(0);
#undef STA
#undef STB
#undef READ_AF
#undef MFMA6

  #pragma unroll
  for (int nn=0;nn<3;nn++){
    int col  = n0 + wc*48 + nn*16 + lr;
    int sel  = col >> 10;
    int colq = col & 1023;
    const float* bp = (sel == 0) ? g.b0 : (sel == 1) ? g.b1 : g.b2;
    float bv = bp[colq];
    ushort* Cq = (ushort*)g.C + (long)sel * 8388608;
    #pragma unroll
    for (int mm=0;mm<8;mm++){
      int row0 = m0 + wr*128 + mm*16 + lk*4;
      #pragma unroll
      for (int i=0;i<4;i++)
        Cq[(long)(row0+i)*1024 + colq] = f2b(acc[mm][nn][i] + bv);
    }
  }
}

// =====================================================================
// scoresX: 256x128 tile on the gemmA_qkv 4-phase skeleton (2 B units).
// P_un = exp(q@k^T/32), causal mask -> 0, bf16 out. Grid = exactly 288
// live blocks (72/batch, triangular decode) -> all CUs busy.
// LDS per buf 48KB (A 4x8KB units + B 2x8KB units); dbuf 96KB.
// Stage: A(t+1) at p0/p1, B(t+2) at p2/p3; counted WAITV(2).
// =====================================================================
__global__ __launch_bounds__(512, 2) void scoresX(GArgs g){
  extern __shared__ char sm[];
  const int tid = threadIdx.x;
  const int wid = tid >> 6, lane = tid & 63;
  const int wr = wid >> 2, wc = wid & 3;
  const int lr = lane & 15, lk = lane >> 4;
  const int f5 = ((lr >> 3) & 1) << 5;

  // triangular decode: bid -> (z, m, n) with n < 2m+2
  const int bid = blockIdx.x;                 // [0, 288)
  const int z   = bid / 72;
  const int idp = bid - z * 72;
  int m = 0;
  #pragma unroll
  for (int mm = 1; mm < 8; ++mm) if (idp >= mm*(mm+1)) m = mm;
  const int n  = idp - m*(m+1);
  const int m0 = m * 256, n0 = n * 128;

  const char* Ab = (const char*)(g.A  + (long)z * g.aBS);
  const char* Bb = (const char*)(g.Bm + (long)z * g.bBS);
  const long lda2 = g.lda * 2, ldb2 = g.ldb * 2;
  const int skk = tid >> 8;
  const int srr = (tid >> 2) & 63;
  const int scc = tid & 3;
  const int scb = (scc * 16) ^ (((srr >> 3) & 1) << 5);
  const char* aU0 = Ab + (long)(m0       + srr)*lda2 + skk*64 + scb;
  const char* aU1 = Ab + (long)(m0 +  64 + srr)*lda2 + skk*64 + scb;
  const char* aU2 = Ab + (long)(m0 + 128 + srr)*lda2 + skk*64 + scb;
  const char* aU3 = Ab + (long)(m0 + 192 + srr)*lda2 + skk*64 + scb;
  const char* bU0 = Bb + (long)(n0       + srr)*ldb2 + skk*64 + scb;
  const char* bU1 = Bb + (long)(n0 +  64 + srr)*ldb2 + skk*64 + scb;
  const int dst = tid * 16;

#define STA(u, cb, k0) gload_lds16(aU##u + (k0)*2, sm + (cb)*49152 + u*8192 + dst)
#define STB(u, cb, k0) gload_lds16(bU##u + (k0)*2, sm + (cb)*49152 + 32768 + u*8192 + dst)

  int aoff[8], boff[2];
  #pragma unroll
  for (int mm=0;mm<8;mm++)
    aoff[mm] = wr*16384 + (mm>>2)*8192 + (mm&3)*1024 + lr*64 + ((lk*16) ^ f5);
  #pragma unroll
  for (int nn=0;nn<2;nn++){
    int br = wc*32 + nn*16 + lr;              // 0..127
    boff[nn] = 32768 + (br>>6)*8192 + (br&63)*64 + ((lk*16) ^ f5);
  }

  f32x4 acc[8][2];
  #pragma unroll
  for (int m2=0;m2<8;m2++)
    #pragma unroll
    for (int n2=0;n2<2;n2++) acc[m2][n2] = f32x4{0.f,0.f,0.f,0.f};

  const int NT = g.K >> 6;                    // 16
  STA(0,0,0); STA(1,0,0); STA(2,0,0); STA(3,0,0);
  STB(0,0,0); STB(1,0,0);
  STB(0,1,64); STB(1,1,64);
  WAITV(2); BAR();

  short8 bf[2][2], af[2][2];
#define READ_AF(MB) \
    af[0][0] = *(const short8*)(base + aoff[MB  ]);        \
    af[0][1] = *(const short8*)(base + aoff[MB  ] + 4096); \
    af[1][0] = *(const short8*)(base + aoff[MB+1]);        \
    af[1][1] = *(const short8*)(base + aoff[MB+1] + 4096);
#define MFMA4(MB) \
    PRIO(1); \
    _Pragma("unroll") \
    for (int kk=0;kk<2;kk++) \
      _Pragma("unroll") \
      for (int mm=0;mm<2;mm++) \
        _Pragma("unroll") \
        for (int nn=0;nn<2;nn++) \
          acc[MB+mm][nn] = __builtin_amdgcn_mfma_f32_16x16x32_bf16(af[mm][kk], bf[nn][kk], acc[MB+mm][nn], 0,0,0); \
    PRIO(0);

  for (int t = 0; t < NT; ++t){
    const int c = t & 1;
    const char* base = sm + c*49152;
    const int kA = ((t+1) < NT ? (t+1) : NT-1) << 6;
    const int kB = ((t+2) < NT ? (t+2) : NT-1) << 6;
    STA(0, c^1, kA); STA(1, c^1, kA);
    #pragma unroll
    for (int nn=0;nn<2;nn++){
      bf[nn][0] = *(const short8*)(base + boff[nn]);
      bf[nn][1] = *(const short8*)(base + boff[nn] + 4096);
    }
    READ_AF(0);
    LGKM0(); SCHEDB();
    MFMA4(0);
    BAR();
    STA(2, c^1, kA); STA(3, c^1, kA);
    READ_AF(2);
    LGKM0(); SCHEDB();
    MFMA4(2);
    BAR();
    STB(0, c, kB);
    READ_AF(4);
    LGKM0(); SCHEDB();
    MFMA4(4);
    BAR();
    STB(1, c, kB);
    READ_AF(6);
    LGKM0(); SCHEDB();
    MFMA4(6);
    WAITV(2);
    BAR();
  }
  WAITV(0);
#undef STA
#undef STB
#undef READ_AF
#undef MFMA4

  // epilogue: P_un = exp(s/32), causal mask, bf16
  const float scale = 0.03125f;
  ushort* Cs = (ushort*)g.C + (long)z * g.cBS;
  #pragma unroll
  for (int nn=0;nn<2;nn++){
    int col = n0 + wc*32 + nn*16 + lr;
    #pragma unroll
    for (int mm=0;mm<8;mm++){
      int row0 = m0 + wr*128 + mm*16 + lk*4;
      #pragma unroll
      for (int i=0;i<4;i++){
        int row = row0 + i;
        float e = (col <= row) ? __expf(acc[mm][nn][i] * scale) : 0.0f;
        Cs[(long)row*g.ldc + col] = f2b(e);
      }
    }
  }
}

// ---------- rowsum: inv[b][row] = 1 / sum_k P_un[b][row][k] ----------
__global__ __launch_bounds__(256) void rowsum_inv(const ushort* __restrict__ P,
                                                  float* __restrict__ inv){
  int row = blockIdx.x & (SEQ-1);
  int b   = blockIdx.x >> 11;
  const short8* pr = (const short8*)(P + ((long)b*SEQ + row)*(long)SEQ);
  int tid = threadIdx.x;
  int lane = tid & 63, wid = tid >> 6;
  float s = 0.f;
  if (tid*8 <= row){
    short8 v = pr[tid];
    #pragma unroll
    for (int j=0;j<8;j++) s += b2f((ushort)v[j]);
  }
  #pragma unroll
  for (int off=1; off<64; off<<=1) s += __shfl_xor(s, off);
  __shared__ float rb[4];
  if (lane == 0) rb[wid] = s;
  __syncthreads();
  if (tid == 0){
    float tot = (rb[0]+rb[1]) + (rb[2]+rb[3]);
    inv[(long)b*SEQ + row] = 1.0f / tot;
  }
}

// =====================================================================
// gemmPV: 128x256 tile, BK=64, 8 waves, 2-phase/K-tile, 96KiB LDS,
// Keff = m0+128; epilogue multiplies inv-rowsum. (r7 verbatim)
// =====================================================================
__global__ __launch_bounds__(512, 2) void gemmPV(GArgs g){
  extern __shared__ char sm[];
  const int m0 = blockIdx.x * 128, n0 = blockIdx.y * 256;
  const int z  = blockIdx.z;
  const int tid = threadIdx.x;
  const int wid = tid >> 6, lane = tid & 63;
  const int wr = wid >> 2, wc = wid & 3;
  const int lr = lane & 15, lk = lane >> 4;
  const int f5 = ((lr >> 3) & 1) << 5;

  const char* Ab = (const char*)(g.A  + (long)z * g.aBS);
  const char* Bb = (const char*)(g.Bm + (long)z * g.bBS);
  const long lda2 = g.lda * 2, ldb2 = g.ldb * 2;
  const int sr  = tid >> 2;
  const int scb = ((lane & 3) << 4) ^ (((sr >> 3) & 1) << 5);
  const char* ar0 = Ab + (long)(m0 + sr)*lda2 + scb;
  const char* br0 = Bb + (long)(n0 + sr      )*ldb2 + scb;
  const char* br1 = Bb + (long)(n0 + 128 + sr)*ldb2 + scb;
  const int dwo = wid << 10;

  auto ST = [&](const char* row, int c, int off, int k0){
    const char* p = row + k0*2;
    char* d = sm + c*49152 + off + dwo;
    gload_lds16(p,      d);
    gload_lds16(p + 64, d + 8192);
  };

  const int aoffs = (wr*64 + lr)*64 + ((lk*16) ^ f5);
  const int boffs = 16384 + (wc>>1)*16384 + ((wc&1)*64 + lr)*64 + ((lk*16) ^ f5);

  f32x4 acc[4][4];
  #pragma unroll
  for (int m=0;m<4;m++)
    #pragma unroll
    for (int n=0;n<4;n++) acc[m][n] = f32x4{0.f,0.f,0.f,0.f};

  const int Keff = m0 + 128;
  const int NT = Keff >> 6;
  ST(ar0, 0, 0, 0);
  ST(br0, 0, 16384, 0); ST(br1, 0, 32768, 0);
  ST(br0, 1, 16384, 64); ST(br1, 1, 32768, 64);
  WAITV(4); BAR();

  for (int t = 0; t < NT; ++t){
    const int c = t & 1;
    const char* base = sm + c*49152;
    const int kA = ((t+1) < NT ? (t+1) : NT-1) << 6;
    const int kB = ((t+2) < NT ? (t+2) : NT-1) << 6;
    short8 bf[4][2], af[2][2];
    ST(ar0, c^1, 0, kA);
    #pragma unroll
    for (int n=0;n<4;n++)
      #pragma unroll
      for (int kk=0;kk<2;kk++)
        bf[n][kk] = *(const short8*)(base + boffs + kk*8192 + n*1024);
    #pragma unroll
    for (int mm=0;mm<2;mm++)
      #pragma unroll
      for (int kk=0;kk<2;kk++)
        af[mm][kk] = *(const short8*)(base + aoffs + kk*8192 + mm*1024);
    LGKM0(); SCHEDB();
    PRIO(1);
    #pragma unroll
    for (int kk=0;kk<2;kk++)
      #pragma unroll
      for (int mm=0;mm<2;mm++)
        #pragma unroll
        for (int n=0;n<4;n++)
          acc[mm][n] = __builtin_amdgcn_mfma_f32_16x16x32_bf16(af[mm][kk], bf[n][kk], acc[mm][n], 0,0,0);
    PRIO(0);
    BAR();
    ST(br0, c, 16384, kB); ST(br1, c, 32768, kB);
    #pragma unroll
    for (int mm=0;mm<2;mm++)
      #pragma unroll
      for (int kk=0;kk<2;kk++)
        af[mm][kk] = *(const short8*)(base + aoffs + kk*8192 + (2+mm)*1024);
    LGKM0(); SCHEDB();
    PRIO(1);
    #pragma unroll
    for (int kk=0;kk<2;kk++)
      #pragma unroll
      for (int mm=0;mm<2;mm++)
        #pragma unroll
        for (int n=0;n<4;n++)
          acc[2+mm][n] = __builtin_amdgcn_mfma_f32_16x16x32_bf16(af[mm][kk], bf[n][kk], acc[2+mm][n], 0,0,0);
    PRIO(0);
    WAITV(4);
    BAR();
  }
  WAITV(0);

  const float* invp = g.b0 + (long)z * SEQ;
  long cz = (long)z * g.cBS;
  #pragma unroll
  for (int m=0;m<4;m++){
    int row0 = m0 + wr*64 + m*16 + lk*4;
    #pragma unroll
    for (int n=0;n<4;n++){
      int col = n0 + wc*64 + n*16 + lr;
      #pragma unroll
      for (int i=0;i<4;i++)
        ((float*)g.C)[cz + (long)(row0+i)*g.ldc + col] = acc[m][n][i] * invp[row0+i];
    }
  }
}

extern "C" void kernel_launch(void* const* d_in, const int* in_sizes, int n_in,
                              void* d_out, int out_size, void* d_ws, size_t ws_size,
                              hipStream_t stream){
  const float* x  = (const float*)d_in[0];
  const float* Wq = (const float*)d_in[1];
  const float* Wk = (const float*)d_in[2];
  const float* Wv = (const float*)d_in[3];
  const float* bq = (const float*)d_in[4];
  const float* bk = (const float*)d_in[5];
  const float* bv = (const float*)d_in[6];
  float* out = (float*)d_out;

  const long XB = 0;            // x bf16 [8192][1024]          16 MB
  const long WT = 16777216;     // Wt bf16 x3 [1024][1024]       6 MB
  const long QB = 23068672;     // q/k/v bf16 contiguous        48 MB
  const long VT = 73400320;     // v^T bf16 [1024][8192]        16 MB
  const long PU = 90177536;     // P_un bf16 [4][2048][2048]    32 MB
  const long IV = 123731968;    // inv rowsum fp32 [4][2048]    32 KB
  const long NEED = 123764736;
  if ((long)ws_size < NEED) return;

  char* ws = (char*)d_ws;
  ushort* xb = (ushort*)(ws + XB);
  ushort* wt = (ushort*)(ws + WT);
  ushort* qb = (ushort*)(ws + QB);
  ushort* kb = qb + 8388608;
  ushort* vb = qb + 16777216;
  ushort* vt = (ushort*)(ws + VT);
  ushort* pu = (ushort*)(ws + PU);
  float*  iv = (float* )(ws + IV);

  hipFuncSetAttribute(reinterpret_cast<const void*>(&gemmA_qkv),
                      hipFuncAttributeMaxDynamicSharedMemorySize, 114688);
  hipFuncSetAttribute(reinterpret_cast<const void*>(&scoresX),
                      hipFuncAttributeMaxDynamicSharedMemorySize, 98304);
  hipFuncSetAttribute(reinterpret_cast<const void*>(&gemmPV),
                      hipFuncAttributeMaxDynamicSharedMemorySize, 98304);

  dim3 tb(32, 8);

  convert_f2b8<<<4096, 256, 0, stream>>>(x, xb);
  transpose_f2b3<<<dim3(32,32,3), tb, 0, stream>>>(Wq, Wk, Wv, wt);

  // fused projections: [q|k|v] = x @ [Wq|Wk|Wv] + bias, M=8192 N=3072 K=1024
  GArgs pa{};
  pa.A = xb; pa.lda = 1024; pa.aBS = 0;
  pa.Bm = wt; pa.ldb = 1024; pa.bBS = 0;
  pa.C = (void*)qb; pa.ldc = 1024; pa.cBS = 0;
  pa.b0 = bq; pa.b1 = bk; pa.b2 = bv;
  pa.K = 1024;
  gemmA_qkv<<<512, 512, 114688, stream>>>(pa);

  transpose_b2b<<<dim3(32,256), tb, 0, stream>>>(vb, vt, 8192, 1024);

  // P_un = exp(q @ k^T / 32), causal-masked, bf16; 256x128 tiles, 288 blocks
  GArgs sa{};
  sa.A = qb;  sa.lda = 1024; sa.aBS = (long)SEQ*1024;
  sa.Bm = kb; sa.ldb = 1024; sa.bBS = (long)SEQ*1024;
  sa.C = (void*)pu; sa.ldc = SEQ; sa.cBS = (long)SEQ*SEQ;
  sa.b0 = nullptr; sa.b1 = nullptr; sa.b2 = nullptr;
  sa.K = 1024;
  scoresX<<<288, 512, 98304, stream>>>(sa);

  rowsum_inv<<<BS*SEQ, 256, 0, stream>>>(pu, iv);

  // out = (P_un @ V) * inv  (B = V^T rows, per-batch col offset; Keff=m0+128)
  GArgs va{};
  va.A = pu;  va.lda = SEQ;  va.aBS = (long)SEQ*SEQ;
  va.Bm = vt; va.ldb = 8192; va.bBS = SEQ;
  va.C = (void*)out; va.ldc = 1024; va.cBS = (long)SEQ*1024;
  va.b0 = iv; va.b1 = nullptr; va.b2 = nullptr;
  va.K = SEQ;
  gemmPV<<<dim3(16,4,4), 512, 98304, stream>>>(va);
}

// Round 14
// 160.361 us; speedup vs baseline: 1.3568x; 1.0960x over previous
//
#include <hip/hip_runtime.h>
#include <cstdint>

#define DEV __device__ __forceinline__

typedef __attribute__((ext_vector_type(4))) float f32x4;
typedef __attribute__((ext_vector_type(8))) short short8;
typedef __attribute__((ext_vector_type(4))) unsigned short u16x4;

constexpr int BS  = 4;
constexpr int SEQ = 2048;

DEV ushort f2b(float f){
  uint32_t u = __builtin_bit_cast(uint32_t, f);
  u += 0x7fffu + ((u >> 16) & 1u);
  return (ushort)(u >> 16);
}

DEV void gload_lds16(const void* g, void* l){
  __builtin_amdgcn_global_load_lds(
      (const __attribute__((address_space(1))) unsigned int*)g,
      (__attribute__((address_space(3))) unsigned int*)l, 16, 0, 0);
}

#define BAR()    __builtin_amdgcn_s_barrier()
#define PRIO(x)  __builtin_amdgcn_s_setprio(x)
#define SCHEDB() __builtin_amdgcn_sched_barrier(0)
#define LGKM0()  asm volatile("s_waitcnt lgkmcnt(0)" ::: "memory")
#define LGKM8()  asm volatile("s_waitcnt lgkmcnt(8)" ::: "memory")
#define WAITV(n) asm volatile("s_waitcnt vmcnt(" #n ")" ::: "memory")

// ---------- fp32 -> bf16 convert ----------
__global__ __launch_bounds__(256) void convert_f2b8(const float* __restrict__ src,
                                                    ushort* __restrict__ dst){
  long i = (long)blockIdx.x * 256 + threadIdx.x;
  const f32x4* s4 = (const f32x4*)src;
  f32x4 a = s4[i*2], b = s4[i*2+1];
  short8 o;
  o[0]=(short)f2b(a[0]); o[1]=(short)f2b(a[1]); o[2]=(short)f2b(a[2]); o[3]=(short)f2b(a[3]);
  o[4]=(short)f2b(b[0]); o[5]=(short)f2b(b[1]); o[6]=(short)f2b(b[2]); o[7]=(short)f2b(b[3]);
  ((short8*)dst)[i] = o;
}

// ---------- fused transpose fp32 [1024][1024] -> bf16 ^T, 3 weights ----------
__global__ __launch_bounds__(256) void transpose_f2b3(const float* __restrict__ w0,
                                                      const float* __restrict__ w1,
                                                      const float* __restrict__ w2,
                                                      ushort* __restrict__ dst){
  __shared__ float t[32][33];
  const int zz = blockIdx.z;
  const float* src = (zz == 0) ? w0 : (zz == 1) ? w1 : w2;
  ushort* d = dst + (long)zz * 1048576;
  int c0 = blockIdx.x * 32, r0 = blockIdx.y * 32;
  int tx = threadIdx.x, ty = threadIdx.y;
  #pragma unroll
  for (int k=0;k<4;k++) t[ty+k*8][tx] = src[(long)(r0+ty+k*8)*1024 + c0+tx];
  __syncthreads();
  #pragma unroll
  for (int k=0;k<4;k++) d[(long)(c0+ty+k*8)*1024 + r0+tx] = f2b(t[tx][ty+k*8]);
}

struct GArgs {
  const ushort* A;  long lda; long aBS;
  const ushort* Bm; long ldb; long bBS;
  void* C;          long ldc; long cBS;
  void* C2;                     // V^T destination (QKV) 
  float* sums;                  // row-sum accumulator (scores/PV)
  const float* b0; const float* b1; const float* b2;
  int K;
};

// =====================================================================
// gemmA_qkv: 256x192 tile, BK=64, 8 waves, 4-phase/K-tile (r4, measured
// 67us). Epilogue: q/k written row-major; V written TRANSPOSED into
// g.C2 ([1024][8192], u16x4 stores) -> transpose_b2b pass deleted.
// =====================================================================
__global__ __launch_bounds__(512, 2) void gemmA_qkv(GArgs g){
  extern __shared__ char sm[];
  const int tid = threadIdx.x;
  const int wid = tid >> 6, lane = tid & 63;
  const int wr = wid >> 2, wc = wid & 3;
  const int lr = lane & 15, lk = lane >> 4;
  const int f5 = ((lr >> 3) & 1) << 5;

  const int fid = blockIdx.x;                 // 512 blocks
  const int xcd = fid & 7, j = fid >> 3;
  const int m0 = (xcd * 4 + (j & 3)) * 256;
  const int n0 = (j >> 2) * 192;

  const long lda2 = g.lda * 2, ldb2 = g.ldb * 2;
  const int skk = tid >> 8;
  const int srr = (tid >> 2) & 63;
  const int scc = tid & 3;
  const int scb = (scc * 16) ^ (((srr >> 3) & 1) << 5);
  const char* aU0 = (const char*)g.A  + (long)(m0       + srr)*lda2 + skk*64 + scb;
  const char* aU1 = (const char*)g.A  + (long)(m0 +  64 + srr)*lda2 + skk*64 + scb;
  const char* aU2 = (const char*)g.A  + (long)(m0 + 128 + srr)*lda2 + skk*64 + scb;
  const char* aU3 = (const char*)g.A  + (long)(m0 + 192 + srr)*lda2 + skk*64 + scb;
  const char* bU0 = (const char*)g.Bm + (long)(n0       + srr)*ldb2 + skk*64 + scb;
  const char* bU1 = (const char*)g.Bm + (long)(n0 +  64 + srr)*ldb2 + skk*64 + scb;
  const char* bU2 = (const char*)g.Bm + (long)(n0 + 128 + srr)*ldb2 + skk*64 + scb;
  const int dst = tid * 16;

#define STA(u, cb, k0) gload_lds16(aU##u + (k0)*2, sm + (cb)*57344 + u*8192 + dst)
#define STB(u, cb, k0) gload_lds16(bU##u + (k0)*2, sm + (cb)*57344 + 32768 + u*8192 + dst)

  int aoff[8], boff[3];
  #pragma unroll
  for (int mm=0;mm<8;mm++)
    aoff[mm] = wr*16384 + (mm>>2)*8192 + (mm&3)*1024 + lr*64 + ((lk*16) ^ f5);
  #pragma unroll
  for (int nn=0;nn<3;nn++){
    int br = wc*48 + nn*16 + lr;
    boff[nn] = 32768 + (br>>6)*8192 + (br&63)*64 + ((lk*16) ^ f5);
  }

  f32x4 acc[8][3];
  #pragma unroll
  for (int m=0;m<8;m++)
    #pragma unroll
    for (int n=0;n<3;n++) acc[m][n] = f32x4{0.f,0.f,0.f,0.f};

  const int NT = g.K >> 6;
  STA(0,0,0); STA(1,0,0); STA(2,0,0); STA(3,0,0);
  STB(0,0,0); STB(1,0,0); STB(2,0,0);
  STB(0,1,64); STB(1,1,64); STB(2,1,64);
  WAITV(3); BAR();

  short8 bf[3][2], af[2][2];
#define READ_AF(MB) \
    af[0][0] = *(const short8*)(base + aoff[MB  ]);        \
    af[0][1] = *(const short8*)(base + aoff[MB  ] + 4096); \
    af[1][0] = *(const short8*)(base + aoff[MB+1]);        \
    af[1][1] = *(const short8*)(base + aoff[MB+1] + 4096);
#define MFMA6(MB) \
    PRIO(1); \
    _Pragma("unroll") \
    for (int kk=0;kk<2;kk++) \
      _Pragma("unroll") \
      for (int mm=0;mm<2;mm++) \
        _Pragma("unroll") \
        for (int nn=0;nn<3;nn++) \
          acc[MB+mm][nn] = __builtin_amdgcn_mfma_f32_16x16x32_bf16(af[mm][kk], bf[nn][kk], acc[MB+mm][nn], 0,0,0); \
    PRIO(0);

  for (int t = 0; t < NT; ++t){
    const int c = t & 1;
    const char* base = sm + c*57344;
    const int kA = ((t+1) < NT ? (t+1) : NT-1) << 6;
    const int kB = ((t+2) < NT ? (t+2) : NT-1) << 6;
    STA(0, c^1, kA); STA(1, c^1, kA);
    #pragma unroll
    for (int nn=0;nn<3;nn++){
      bf[nn][0] = *(const short8*)(base + boff[nn]);
      bf[nn][1] = *(const short8*)(base + boff[nn] + 4096);
    }
    READ_AF(0);
    LGKM0(); SCHEDB();
    MFMA6(0);
    BAR();
    STA(2, c^1, kA); STA(3, c^1, kA);
    READ_AF(2);
    LGKM0(); SCHEDB();
    MFMA6(2);
    BAR();
    STB(0, c, kB); STB(1, c, kB);
    READ_AF(4);
    LGKM0(); SCHEDB();
    MFMA6(4);
    BAR();
    STB(2, c, kB);
    READ_AF(6);
    LGKM0(); SCHEDB();
    MFMA6(6);
    WAITV(3);
    BAR();
  }
  WAITV(0);
#undef STA
#undef STB
#undef READ_AF
#undef MFMA6

  #pragma unroll
  for (int nn=0;nn<3;nn++){
    int col  = n0 + wc*48 + nn*16 + lr;
    int sel  = col >> 10;                     // wave-uniform per nn (16-aligned frag)
    int colq = col & 1023;
    const float* bp = (sel == 0) ? g.b0 : (sel == 1) ? g.b1 : g.b2;
    float bv = bp[colq];
    if (sel == 2){
      ushort* Vt = (ushort*)g.C2;             // [1024][8192]
      #pragma unroll
      for (int mm=0;mm<8;mm++){
        int row0 = m0 + wr*128 + mm*16 + lk*4;
        u16x4 o;
        #pragma unroll
        for (int i=0;i<4;i++) o[i] = f2b(acc[mm][nn][i] + bv);
        *(u16x4*)(Vt + (long)colq*8192 + row0) = o;
      }
    } else {
      ushort* Cq = (ushort*)g.C + (long)sel * 8388608;
      #pragma unroll
      for (int mm=0;mm<8;mm++){
        int row0 = m0 + wr*128 + mm*16 + lk*4;
        #pragma unroll
        for (int i=0;i<4;i++)
          Cq[(long)(row0+i)*1024 + colq] = f2b(acc[mm][nn][i] + bv);
      }
    }
  }
}

// =====================================================================
// scores8p: 256x256 q@k^T per batch (r7 skeleton, measured in 169.5us
// total). Epilogue: P_un = exp(s/32) causal-masked bf16 AND per-row
// partial sums reduced in-wave (shfl over 16 lanes) + one atomicAdd
// per row per wave into g.sums -> rowsum pass deleted.
// =====================================================================
__global__ __launch_bounds__(512, 2) void scores8p(GArgs g){
  extern __shared__ char sm[];
  const int m0 = blockIdx.x * 256, n0 = blockIdx.y * 256;
  const int z  = blockIdx.z;
  if (n0 > m0) return;
  const int tid = threadIdx.x;
  const int wid = tid >> 6, lane = tid & 63;
  const int wr = wid >> 2, wc = wid & 3;
  const int lr = lane & 15, lk = lane >> 4;

  const char* Ab = (const char*)(g.A  + (long)z * g.aBS);
  const char* Bb = (const char*)(g.Bm + (long)z * g.bBS);
  const long lda2 = g.lda * 2, ldb2 = g.ldb * 2;
  const int srow = tid >> 2;
  const int scol = ((tid & 3) << 4) ^ (((tid >> 5) & 1) << 5);
  const char* sA = Ab + (long)(m0 + srow) * lda2 + scol;
  const char* sB = Bb + (long)(n0 + srow) * ldb2 + scol;
  const int dst16 = tid << 4;

  auto STAGE = [&](int tt, int which){
    const char* s = (which < 2)
        ? sA + (long)(which & 1) * 128 * lda2 + (long)tt * 128
        : sB + (long)(which & 1) * 128 * ldb2 + (long)tt * 128;
    char* d = sm + (tt & 1) * 65536 + which * 16384 + dst16;
    gload_lds16(s,      d);
    gload_lds16(s + 64, d + 8192);
  };

  int aoff[8], boff[4];
  #pragma unroll
  for (int mm = 0; mm < 8; mm++){
    int r = mm * 16 + lr;
    aoff[mm] = wr * 16384 + r * 64 + ((lk * 16) ^ (((r >> 3) & 1) << 5));
  }
  #pragma unroll
  for (int nn = 0; nn < 4; nn++){
    int rb = wc * 64 + nn * 16 + lr;
    boff[nn] = 32768 + (rb >> 7) * 16384 + (rb & 127) * 64
             + ((lk * 16) ^ (((rb >> 3) & 1) << 5));
  }

  f32x4 acc[8][4];
  #pragma unroll
  for (int m = 0; m < 8; m++)
    #pragma unroll
    for (int n = 0; n < 4; n++) acc[m][n] = f32x4{0.f,0.f,0.f,0.f};

  const int NT = g.K >> 6;                      // 16
  STAGE(0,2); STAGE(0,3); STAGE(0,0); STAGE(0,1);
  STAGE(1,2); STAGE(1,3);
  WAITV(4); BAR();

  short8 af[2][2], bf[4][2];
#define READ_A(MB) \
    af[0][0] = *(const short8*)(base + aoff[MB]);            \
    af[0][1] = *(const short8*)(base + aoff[MB] + 8192);     \
    af[1][0] = *(const short8*)(base + aoff[MB+1]);          \
    af[1][1] = *(const short8*)(base + aoff[MB+1] + 8192);
#define MFMA16(MB) \
    PRIO(1); \
    _Pragma("unroll") \
    for (int kk = 0; kk < 2; kk++) \
      _Pragma("unroll") \
      for (int mm = 0; mm < 2; mm++) \
        _Pragma("unroll") \
        for (int nn = 0; nn < 4; nn++) \
          acc[MB+mm][nn] = __builtin_amdgcn_mfma_f32_16x16x32_bf16(af[mm][kk], bf[nn][kk], acc[MB+mm][nn], 0,0,0); \
    PRIO(0);

  for (int t = 0; t < NT; ++t){
    const char* base = sm + (t & 1) * 65536;
    if (t + 1 < NT) STAGE(t+1, 0);
    #pragma unroll
    for (int nn = 0; nn < 4; nn++){
      bf[nn][0] = *(const short8*)(base + boff[nn]);
      bf[nn][1] = *(const short8*)(base + boff[nn] + 8192);
    }
    READ_A(0);
    LGKM8();
    SCHEDB(); BAR(); LGKM0(); SCHEDB();
    MFMA16(0);
    SCHEDB(); BAR();
    if (t + 1 < NT) STAGE(t+1, 1);
    READ_A(2);
    SCHEDB(); BAR(); LGKM0(); SCHEDB();
    MFMA16(2);
    SCHEDB(); BAR();
    if (t + 2 < NT) STAGE(t+2, 2);
    READ_A(4);
    SCHEDB(); BAR(); LGKM0(); SCHEDB();
    MFMA16(4);
    SCHEDB(); BAR();
    if (t + 2 < NT) STAGE(t+2, 3);
    READ_A(6);
    SCHEDB(); BAR(); LGKM0(); SCHEDB();
    MFMA16(6);
    WAITV(4);
    SCHEDB(); BAR();
  }
#undef READ_A
#undef MFMA16

  // epilogue: P_un = exp(s/32) masked, bf16 out; fused row-sum partials
  const float scale = 0.03125f;
  ushort* Cs = (ushort*)g.C + (long)z * g.cBS;
  float* sums = g.sums + (long)z * SEQ;
  #pragma unroll
  for (int mm = 0; mm < 8; mm++){
    int row0 = m0 + wr*128 + mm*16 + lk*4;
    #pragma unroll
    for (int i = 0; i < 4; i++){
      int row = row0 + i;
      float s = 0.f;
      #pragma unroll
      for (int nn = 0; nn < 4; nn++){
        int col = n0 + wc*64 + nn*16 + lr;
        float e = (col <= row) ? __expf(acc[mm][nn][i] * scale) : 0.0f;
        Cs[(long)row*g.ldc + col] = f2b(e);
        s += e;
      }
      s += __shfl_xor(s, 1); s += __shfl_xor(s, 2);
      s += __shfl_xor(s, 4); s += __shfl_xor(s, 8);
      if (lr == 0) atomicAdd(&sums[row], s);
    }
  }
}

// =====================================================================
// gemmPV: 128x256 tile, BK=64, 8 waves, 2-phase/K-tile, 96KiB LDS,
// Keff = m0+128; epilogue divides by row-sum (g.sums). (r7 structure)
// =====================================================================
__global__ __launch_bounds__(512, 2) void gemmPV(GArgs g){
  extern __shared__ char sm[];
  const int m0 = blockIdx.x * 128, n0 = blockIdx.y * 256;
  const int z  = blockIdx.z;
  const int tid = threadIdx.x;
  const int wid = tid >> 6, lane = tid & 63;
  const int wr = wid >> 2, wc = wid & 3;
  const int lr = lane & 15, lk = lane >> 4;
  const int f5 = ((lr >> 3) & 1) << 5;

  const char* Ab = (const char*)(g.A  + (long)z * g.aBS);
  const char* Bb = (const char*)(g.Bm + (long)z * g.bBS);
  const long lda2 = g.lda * 2, ldb2 = g.ldb * 2;
  const int sr  = tid >> 2;
  const int scb = ((lane & 3) << 4) ^ (((sr >> 3) & 1) << 5);
  const char* ar0 = Ab + (long)(m0 + sr)*lda2 + scb;
  const char* br0 = Bb + (long)(n0 + sr      )*ldb2 + scb;
  const char* br1 = Bb + (long)(n0 + 128 + sr)*ldb2 + scb;
  const int dwo = wid << 10;

  auto ST = [&](const char* row, int c, int off, int k0){
    const char* p = row + k0*2;
    char* d = sm + c*49152 + off + dwo;
    gload_lds16(p,      d);
    gload_lds16(p + 64, d + 8192);
  };

  const int aoffs = (wr*64 + lr)*64 + ((lk*16) ^ f5);
  const int boffs = 16384 + (wc>>1)*16384 + ((wc&1)*64 + lr)*64 + ((lk*16) ^ f5);

  f32x4 acc[4][4];
  #pragma unroll
  for (int m=0;m<4;m++)
    #pragma unroll
    for (int n=0;n<4;n++) acc[m][n] = f32x4{0.f,0.f,0.f,0.f};

  const int Keff = m0 + 128;
  const int NT = Keff >> 6;
  ST(ar0, 0, 0, 0);
  ST(br0, 0, 16384, 0); ST(br1, 0, 32768, 0);
  ST(br0, 1, 16384, 64); ST(br1, 1, 32768, 64);
  WAITV(4); BAR();

  for (int t = 0; t < NT; ++t){
    const int c = t & 1;
    const char* base = sm + c*49152;
    const int kA = ((t+1) < NT ? (t+1) : NT-1) << 6;
    const int kB = ((t+2) < NT ? (t+2) : NT-1) << 6;
    short8 bf[4][2], af[2][2];
    ST(ar0, c^1, 0, kA);
    #pragma unroll
    for (int n=0;n<4;n++)
      #pragma unroll
      for (int kk=0;kk<2;kk++)
        bf[n][kk] = *(const short8*)(base + boffs + kk*8192 + n*1024);
    #pragma unroll
    for (int mm=0;mm<2;mm++)
      #pragma unroll
      for (int kk=0;kk<2;kk++)
        af[mm][kk] = *(const short8*)(base + aoffs + kk*8192 + mm*1024);
    LGKM0(); SCHEDB();
    PRIO(1);
    #pragma unroll
    for (int kk=0;kk<2;kk++)
      #pragma unroll
      for (int mm=0;mm<2;mm++)
        #pragma unroll
        for (int n=0;n<4;n++)
          acc[mm][n] = __builtin_amdgcn_mfma_f32_16x16x32_bf16(af[mm][kk], bf[n][kk], acc[mm][n], 0,0,0);
    PRIO(0);
    BAR();
    ST(br0, c, 16384, kB); ST(br1, c, 32768, kB);
    #pragma unroll
    for (int mm=0;mm<2;mm++)
      #pragma unroll
      for (int kk=0;kk<2;kk++)
        af[mm][kk] = *(const short8*)(base + aoffs + kk*8192 + (2+mm)*1024);
    LGKM0(); SCHEDB();
    PRIO(1);
    #pragma unroll
    for (int kk=0;kk<2;kk++)
      #pragma unroll
      for (int mm=0;mm<2;mm++)
        #pragma unroll
        for (int n=0;n<4;n++)
          acc[2+mm][n] = __builtin_amdgcn_mfma_f32_16x16x32_bf16(af[mm][kk], bf[n][kk], acc[2+mm][n], 0,0,0);
    PRIO(0);
    WAITV(4);
    BAR();
  }
  WAITV(0);

  const float* sums = g.sums + (long)z * SEQ;
  long cz = (long)z * g.cBS;
  #pragma unroll
  for (int m=0;m<4;m++){
    int row0 = m0 + wr*64 + m*16 + lk*4;
    float iv4[4];
    #pragma unroll
    for (int i=0;i<4;i++) iv4[i] = 1.0f / sums[row0+i];
    #pragma unroll
    for (int n=0;n<4;n++){
      int col = n0 + wc*64 + n*16 + lr;
      #pragma unroll
      for (int i=0;i<4;i++)
        ((float*)g.C)[cz + (long)(row0+i)*g.ldc + col] = acc[m][n][i] * iv4[i];
    }
  }
}

extern "C" void kernel_launch(void* const* d_in, const int* in_sizes, int n_in,
                              void* d_out, int out_size, void* d_ws, size_t ws_size,
                              hipStream_t stream){
  const float* x  = (const float*)d_in[0];
  const float* Wq = (const float*)d_in[1];
  const float* Wk = (const float*)d_in[2];
  const float* Wv = (const float*)d_in[3];
  const float* bq = (const float*)d_in[4];
  const float* bk = (const float*)d_in[5];
  const float* bv = (const float*)d_in[6];
  float* out = (float*)d_out;

  const long XB = 0;            // x bf16 [8192][1024]          16 MB
  const long WT = 16777216;     // Wt bf16 x3 [1024][1024]       6 MB
  const long QB = 23068672;     // q/k bf16 (v slot unused)     48 MB
  const long VT = 73400320;     // v^T bf16 [1024][8192]        16 MB
  const long PU = 90177536;     // P_un bf16 [4][2048][2048]    32 MB
  const long IV = 123731968;    // row sums fp32 [4][2048]      32 KB
  const long NEED = 123764736;
  if ((long)ws_size < NEED) return;

  char* ws = (char*)d_ws;
  ushort* xb = (ushort*)(ws + XB);
  ushort* wt = (ushort*)(ws + WT);
  ushort* qb = (ushort*)(ws + QB);
  ushort* kb = qb + 8388608;
  ushort* vt = (ushort*)(ws + VT);
  ushort* pu = (ushort*)(ws + PU);
  float*  iv = (float* )(ws + IV);

  hipFuncSetAttribute(reinterpret_cast<const void*>(&gemmA_qkv),
                      hipFuncAttributeMaxDynamicSharedMemorySize, 114688);
  hipFuncSetAttribute(reinterpret_cast<const void*>(&scores8p),
                      hipFuncAttributeMaxDynamicSharedMemorySize, 131072);
  hipFuncSetAttribute(reinterpret_cast<const void*>(&gemmPV),
                      hipFuncAttributeMaxDynamicSharedMemorySize, 98304);

  dim3 tb(32, 8);

  hipMemsetAsync(iv, 0, BS*SEQ*sizeof(float), stream);   // zero row-sum acc
  convert_f2b8<<<4096, 256, 0, stream>>>(x, xb);
  transpose_f2b3<<<dim3(32,32,3), tb, 0, stream>>>(Wq, Wk, Wv, wt);

  // fused projections: q/k row-major + V transposed, bias fused
  GArgs pa{};
  pa.A = xb; pa.lda = 1024; pa.aBS = 0;
  pa.Bm = wt; pa.ldb = 1024; pa.bBS = 0;
  pa.C = (void*)qb; pa.ldc = 1024; pa.cBS = 0;
  pa.C2 = (void*)vt; pa.sums = nullptr;
  pa.b0 = bq; pa.b1 = bk; pa.b2 = bv;
  pa.K = 1024;
  gemmA_qkv<<<512, 512, 114688, stream>>>(pa);

  // P_un = exp(q @ k^T / 32) causal-masked bf16 + fused row-sum partials
  GArgs sa{};
  sa.A = qb;  sa.lda = 1024; sa.aBS = (long)SEQ*1024;
  sa.Bm = kb; sa.ldb = 1024; sa.bBS = (long)SEQ*1024;
  sa.C = (void*)pu; sa.ldc = SEQ; sa.cBS = (long)SEQ*SEQ;
  sa.C2 = nullptr; sa.sums = iv;
  sa.b0 = nullptr; sa.b1 = nullptr; sa.b2 = nullptr;
  sa.K = 1024;
  scores8p<<<dim3(8,8,4), 512, 131072, stream>>>(sa);

  // out = (P_un @ V) / rowsum  (B = V^T rows; Keff=m0+128)
  GArgs va{};
  va.A = pu;  va.lda = SEQ;  va.aBS = (long)SEQ*SEQ;
  va.Bm = vt; va.ldb = 8192; va.bBS = SEQ;
  va.C = (void*)out; va.ldc = 1024; va.cBS = (long)SEQ*1024;
  va.C2 = nullptr; va.sums = iv;
  va.b0 = nullptr; va.b1 = nullptr; va.b2 = nullptr;
  va.K = SEQ;
  gemmPV<<<dim3(16,4,4), 512, 98304, stream>>>(va);
}